// Round 10
// baseline (196.045 us; speedup 1.0000x reference)
//
#include <hip/hip_runtime.h>

#define NF    50000
#define PADP  50001
#define KN    9
#define KTOT  2304
#define NCHUNK 782
#define NT    72          // 2304/32 K-tiles
#define BM    128
#define NBLK  391         // ceil(50000/128)
#define DUMMY 32768       // dummy LDS slot (tail stages)
#define IDXOFF 40960

// ---- ws layout (bytes) ----
#define WT_OFF   0u          // 256*2304*2 = 1179648
#define FLAG_OFF 1179648u
#define CNT_OFF  1179904u    // 782*4
#define PADX_OFF 1183744u    // 50001*256*2

typedef float f32x4 __attribute__((ext_vector_type(4)));
typedef __bf16 bf16x8 __attribute__((ext_vector_type(8)));

typedef const __attribute__((address_space(1))) unsigned int* gas_t;
typedef __attribute__((address_space(3))) unsigned int* las_t;

static __device__ __forceinline__ void gll16(const void* g, void* l) {
  __builtin_amdgcn_global_load_lds((gas_t)g, (las_t)l, 16, 0, 0);
}

static __device__ __forceinline__ unsigned short f2bf(float f) {
  unsigned int u = __builtin_bit_cast(unsigned int, f);
  u = u + 0x7fffu + ((u >> 16) & 1u);      // RNE
  return (unsigned short)(u >> 16);
}

// ---------- preprocessing ----------

__global__ void k_prep(const float* __restrict__ w, unsigned short* __restrict__ wt,
                       const unsigned char* __restrict__ pad, int* __restrict__ cnt,
                       const unsigned int* __restrict__ raw, int* __restrict__ flag) {
  if (blockIdx.x < 256) {
    int o = blockIdx.x;
    int i = threadIdx.x;
    const float* wr = w + (o * 256 + i) * 9;
    float wv[9];
    float s = 0.f;
#pragma unroll
    for (int k = 0; k < 9; ++k) { wv[k] = wr[k]; s += wv[k] * wv[k]; }
#pragma unroll
    for (int d = 32; d >= 1; d >>= 1) s += __shfl_xor(s, d);
    __shared__ float red[4];
    if ((i & 63) == 0) red[i >> 6] = s;
    __syncthreads();
    float dc = rsqrtf(red[0] + red[1] + red[2] + red[3] + 1e-8f);
#pragma unroll
    for (int k = 0; k < 9; ++k)
      wt[o * KTOT + k * 256 + i] = f2bf(wv[k] * dc);
  } else {
    int cb = blockIdx.x - 256;
    int t = cb * 256 + threadIdx.x;
    bool ip = (t < PADP) ? (pad[t] != 0) : true;
    unsigned long long m = __ballot(ip);
    int c = t >> 6;
    if ((threadIdx.x & 63) == 0 && c < NCHUNK) cnt[c] = __popcll(m);
    if (cb == 0 && threadIdx.x < 64) {
      unsigned int v = raw[threadIdx.x * 2 + 1];
      unsigned long long nz = __ballot(v != 0u);
      if (threadIdx.x == 0) flag[0] = (nz == 0ull) ? 1 : 0;
    }
  }
}

__global__ __launch_bounds__(256) void k_rankpadx(
    const float* __restrict__ x, const unsigned char* __restrict__ pad,
    const int* __restrict__ cnt, unsigned short* __restrict__ padx) {
  const int c = blockIdx.x;
  const int tid = threadIdx.x, w = tid >> 6, lane = tid & 63;
  int s = 0;
  for (int i = tid; i < c; i += 256) s += cnt[i];
#pragma unroll
  for (int d = 32; d >= 1; d >>= 1) s += __shfl_xor(s, d);
  __shared__ int red[4];
  __shared__ int rnk[64];
  if (lane == 0) red[w] = s;
  __syncthreads();
  const int S = red[0] + red[1] + red[2] + red[3];
  if (w == 0) {
    int p = c * 64 + lane;
    bool ip = (p < PADP) ? (pad[p] != 0) : true;
    unsigned long long m = __ballot(ip);
    int before = __popcll(m & ((1ull << lane) - 1ull));
    rnk[lane] = ip ? -1 : (p - (S + before));
  }
  __syncthreads();
  const int col = lane * 4;
#pragma unroll
  for (int i = 0; i < 16; ++i) {
    int rl = i * 4 + w;
    int pp = c * 64 + rl;
    if (pp >= PADP) continue;
    int rr = rnk[rl];
    ushort4 ov;
    if (rr < 0) { ov.x = 0; ov.y = 0; ov.z = 0; ov.w = 0; }
    else {
      const float4 v = *(const float4*)(x + rr * 256 + col);
      ov.x = f2bf(v.x); ov.y = f2bf(v.y); ov.z = f2bf(v.z); ov.w = f2bf(v.w);
    }
    *(ushort4*)(padx + pp * 256 + col) = ov;
  }
}

// ---------- main gathered GEMM ----------
// BM=128 x BN=256 x BK=32, 512 thr (8 waves 2M x 4N), wave-tile 64x64 (4x4).
// LDS carries ONLY A: ring-4 x 8KB + dummy slot, 1 gll16/thread/tile, lead-3,
// counted vmcnt, ONE raw s_barrier per tile.
// B: direct L2->register, 4 dwordx4/wave/tile, ping-pong sets, 1-tile lead,
// per-wave private (no barrier involvement; compiler inserts its dep waits).
// Per-iter vmem order (pinned): [B(t+1) x4][gll16 A(t+3)] -> A(t) ready at
// vmcnt(10) steady (t=0: 2, t=1: 6). LDS/tile: 32KB read + 8KB write (~470cy)
// vs MFMA 310cy -> ceiling ~65% (was 88KB/1035cy -> 30% in R1-R9).
__global__ __launch_bounds__(512, 3) void k_main(
    const unsigned short* __restrict__ padx,   // [50001][256] bf16
    const unsigned short* __restrict__ wt,     // [256][2304] bf16
    const void* __restrict__ nbr,              // [50000][9] int64 or int32
    const int* __restrict__ flag,
    const float* __restrict__ bias,            // [256]
    float* __restrict__ out) {                 // [50000][256] f32
  __shared__ __align__(16) unsigned char sm[45568];
  const int tid = threadIdx.x;
  const int wv = tid >> 6, lane = tid & 63;
  const int m0 = blockIdx.x * BM;
  int* idx_lds = (int*)(sm + IDXOFF);          // 128*9 ints

  const int q = lane & 15, hi = lane >> 4;
  const int wm = wv >> 2, wn = wv & 3;

  // bias preload (drained by the idx __syncthreads -> vmem queue starts clean)
  float bv[4];
#pragma unroll
  for (int ni = 0; ni < 4; ++ni) bv[ni] = bias[wn * 64 + ni * 16 + q];

  // idx cache
  const bool f64 = (flag[0] != 0);
  const long long* n64 = (const long long*)nbr;
  const int* n32 = (const int*)nbr;
  for (int e = tid; e < BM * 9; e += 512) {
    int f = m0 + e / 9;
    if (f >= NF) f = NF - 1;
    int k = e - (e / 9) * 9;
    idx_lds[e] = f64 ? (int)n64[f * KN + k] : n32[f * KN + k];
  }
  __syncthreads();

  // ---- A staging: 1 gll16/thread/tile, lane-linear dest, src-side swizzle ----
  const int rA = tid >> 2;                                  // LDS row 0..127
  const int srcsl = ((tid & 3) ^ ((tid >> 3) & 3)) * 8;     // swizzled src slot (elems)
  const int aDst = tid * 16;

  // ---- A fragment read offsets (R1-verified conflict-free) ----
  const int slotb = (hi ^ ((q >> 1) & 3)) * 16;
  int aoff[4];
#pragma unroll
  for (int mi = 0; mi < 4; ++mi) aoff[mi] = (wm * 64 + mi * 16 + q) * 64 + slotb;

  // ---- B direct-load bases: lane (q,hi) reads wt[col(q)][k + hi*8], 16B ----
  const unsigned short* wB0 = wt + (wn * 64 +  0 + q) * KTOT + hi * 8;
  const unsigned short* wB1 = wt + (wn * 64 + 16 + q) * KTOT + hi * 8;
  const unsigned short* wB2 = wt + (wn * 64 + 32 + q) * KTOT + hi * 8;
  const unsigned short* wB3 = wt + (wn * 64 + 48 + q) * KTOT + hi * 8;

  f32x4 acc[4][4];
#pragma unroll
  for (int a = 0; a < 4; ++a)
#pragma unroll
    for (int b = 0; b < 4; ++b) {
      acc[a][b][0] = 0.f; acc[a][b][1] = 0.f; acc[a][b][2] = 0.f; acc[a][b][3] = 0.f;
    }

  int pc = idx_lds[rA * 9 + 0];
  int pn = pc;

  // ---- prologue (order pinned): B(0) x4, then gll16 A(0),A(1),A(2) ----
  bf16x8 bA0 = *(const bf16x8*)(wB0);
  bf16x8 bA1 = *(const bf16x8*)(wB1);
  bf16x8 bA2 = *(const bf16x8*)(wB2);
  bf16x8 bA3 = *(const bf16x8*)(wB3);
  __builtin_amdgcn_sched_barrier(0);
  gll16(padx + pc * 256 +  0 + srcsl, sm +     0 + aDst);
  __builtin_amdgcn_sched_barrier(0);
  gll16(padx + pc * 256 + 32 + srcsl, sm +  8192 + aDst);
  __builtin_amdgcn_sched_barrier(0);
  gll16(padx + pc * 256 + 64 + srcsl, sm + 16384 + aDst);
  __builtin_amdgcn_sched_barrier(0);
  bf16x8 bB0 = bA0, bB1 = bA1, bB2 = bA2, bB3 = bA3;

#define ITER(J, WSTR, cB0,cB1,cB2,cB3, nB0,nB1,nB2,nB3) {               \
    asm volatile("s_waitcnt vmcnt(" WSTR ")" ::: "memory");             \
    __builtin_amdgcn_s_barrier();                                       \
    __builtin_amdgcn_sched_barrier(0);                                  \
    const int t_ = g8 + (J);                                            \
    const unsigned char* rb_ = sm + (t_ & 3) * 8192;                    \
    bf16x8 af0_ = *(const bf16x8*)(rb_ + aoff[0]);                      \
    bf16x8 af1_ = *(const bf16x8*)(rb_ + aoff[1]);                      \
    bf16x8 af2_ = *(const bf16x8*)(rb_ + aoff[2]);                      \
    bf16x8 af3_ = *(const bf16x8*)(rb_ + aoff[3]);                      \
    const int kB_ = ((t_ + 1 < NT) ? t_ + 1 : NT - 1) * 32;             \
    nB0 = *(const bf16x8*)(wB0 + kB_);                                  \
    nB1 = *(const bf16x8*)(wB1 + kB_);                                  \
    nB2 = *(const bf16x8*)(wB2 + kB_);                                  \
    nB3 = *(const bf16x8*)(wB3 + kB_);                                  \
    __builtin_amdgcn_sched_barrier(0);                                  \
    {                                                                   \
      const int u_ = t_ + 3;                                            \
      const int p_ = ((J) < 5) ? pc : pn;                               \
      unsigned char* wdst_ = (u_ < NT) ? (sm + (u_ & 3) * 8192 + aDst)  \
                                       : (sm + DUMMY + aDst);           \
      const int kc_ = (u_ & 7) * 32;                                    \
      gll16(padx + p_ * 256 + kc_ + srcsl, wdst_);                      \
    }                                                                   \
    if ((J) == 0) pn = idx_lds[rA * 9 + ((g >= 8) ? 8 : g + 1)];        \
    __builtin_amdgcn_sched_barrier(0);                                  \
    __builtin_amdgcn_s_setprio(1);                                      \
    acc[0][0] = __builtin_amdgcn_mfma_f32_16x16x32_bf16(af0_, cB0, acc[0][0], 0,0,0); \
    acc[0][1] = __builtin_amdgcn_mfma_f32_16x16x32_bf16(af0_, cB1, acc[0][1], 0,0,0); \
    acc[0][2] = __builtin_amdgcn_mfma_f32_16x16x32_bf16(af0_, cB2, acc[0][2], 0,0,0); \
    acc[0][3] = __builtin_amdgcn_mfma_f32_16x16x32_bf16(af0_, cB3, acc[0][3], 0,0,0); \
    acc[1][0] = __builtin_amdgcn_mfma_f32_16x16x32_bf16(af1_, cB0, acc[1][0], 0,0,0); \
    acc[1][1] = __builtin_amdgcn_mfma_f32_16x16x32_bf16(af1_, cB1, acc[1][1], 0,0,0); \
    acc[1][2] = __builtin_amdgcn_mfma_f32_16x16x32_bf16(af1_, cB2, acc[1][2], 0,0,0); \
    acc[1][3] = __builtin_amdgcn_mfma_f32_16x16x32_bf16(af1_, cB3, acc[1][3], 0,0,0); \
    acc[2][0] = __builtin_amdgcn_mfma_f32_16x16x32_bf16(af2_, cB0, acc[2][0], 0,0,0); \
    acc[2][1] = __builtin_amdgcn_mfma_f32_16x16x32_bf16(af2_, cB1, acc[2][1], 0,0,0); \
    acc[2][2] = __builtin_amdgcn_mfma_f32_16x16x32_bf16(af2_, cB2, acc[2][2], 0,0,0); \
    acc[2][3] = __builtin_amdgcn_mfma_f32_16x16x32_bf16(af2_, cB3, acc[2][3], 0,0,0); \
    acc[3][0] = __builtin_amdgcn_mfma_f32_16x16x32_bf16(af3_, cB0, acc[3][0], 0,0,0); \
    acc[3][1] = __builtin_amdgcn_mfma_f32_16x16x32_bf16(af3_, cB1, acc[3][1], 0,0,0); \
    acc[3][2] = __builtin_amdgcn_mfma_f32_16x16x32_bf16(af3_, cB2, acc[3][2], 0,0,0); \
    acc[3][3] = __builtin_amdgcn_mfma_f32_16x16x32_bf16(af3_, cB3, acc[3][3], 0,0,0); \
    __builtin_amdgcn_s_setprio(0);                                      \
  }

  // group 0 (peeled waits: t=0 -> 2, t=1 -> 6, then steady 10)
  {
    const int g = 0, g8 = 0;
    ITER(0, "2",  bA0,bA1,bA2,bA3, bB0,bB1,bB2,bB3)
    ITER(1, "6",  bB0,bB1,bB2,bB3, bA0,bA1,bA2,bA3)
    ITER(2, "10", bA0,bA1,bA2,bA3, bB0,bB1,bB2,bB3)
    ITER(3, "10", bB0,bB1,bB2,bB3, bA0,bA1,bA2,bA3)
    ITER(4, "10", bA0,bA1,bA2,bA3, bB0,bB1,bB2,bB3)
    ITER(5, "10", bB0,bB1,bB2,bB3, bA0,bA1,bA2,bA3)
    ITER(6, "10", bA0,bA1,bA2,bA3, bB0,bB1,bB2,bB3)
    ITER(7, "10", bB0,bB1,bB2,bB3, bA0,bA1,bA2,bA3)
    pc = pn;
  }
#pragma unroll 1
  for (int g = 1; g < 9; ++g) {
    const int g8 = g * 8;
    ITER(0, "10", bA0,bA1,bA2,bA3, bB0,bB1,bB2,bB3)
    ITER(1, "10", bB0,bB1,bB2,bB3, bA0,bA1,bA2,bA3)
    ITER(2, "10", bA0,bA1,bA2,bA3, bB0,bB1,bB2,bB3)
    ITER(3, "10", bB0,bB1,bB2,bB3, bA0,bA1,bA2,bA3)
    ITER(4, "10", bA0,bA1,bA2,bA3, bB0,bB1,bB2,bB3)
    ITER(5, "10", bB0,bB1,bB2,bB3, bA0,bA1,bA2,bA3)
    ITER(6, "10", bA0,bA1,bA2,bA3, bB0,bB1,bB2,bB3)
    ITER(7, "10", bB0,bB1,bB2,bB3, bA0,bA1,bA2,bA3)
    pc = pn;
  }
#undef ITER
  asm volatile("s_waitcnt vmcnt(0)" ::: "memory");

  // ---- epilogue: bias + store (D: col = q, row = hi*4 + r) ----
#pragma unroll
  for (int ni = 0; ni < 4; ++ni) {
    const int col = wn * 64 + ni * 16 + q;
#pragma unroll
    for (int mi = 0; mi < 4; ++mi) {
#pragma unroll
      for (int rr = 0; rr < 4; ++rr) {
        const int row = m0 + wm * 64 + mi * 16 + hi * 4 + rr;
        if (row < NF) out[row * 256 + col] = acc[mi][ni][rr] + bv[ni];
      }
    }
  }
}

extern "C" void kernel_launch(void* const* d_in, const int* in_sizes, int n_in,
                              void* d_out, int out_size, void* d_ws, size_t ws_size,
                              hipStream_t stream) {
  const float* x = (const float*)d_in[0];
  const float* wfull = (const float*)d_in[1];
  const float* bias = (const float*)d_in[2];
  const void* nbr = d_in[3];
  const unsigned char* pad = (const unsigned char*)d_in[4];
  float* out = (float*)d_out;
  char* ws = (char*)d_ws;

  unsigned short* wt   = (unsigned short*)(ws + WT_OFF);
  int* flag            = (int*)(ws + FLAG_OFF);
  int* cnt             = (int*)(ws + CNT_OFF);
  unsigned short* padx = (unsigned short*)(ws + PADX_OFF);

  k_prep<<<452, 256, 0, stream>>>(wfull, wt, pad, cnt, (const unsigned int*)nbr, flag);
  k_rankpadx<<<NCHUNK, 256, 0, stream>>>(x, pad, cnt, padx);
  k_main<<<NBLK, 512, 0, stream>>>(padx, wt, nbr, flag, bias, out);
}

// Round 11
// 87.680 us; speedup vs baseline: 2.2359x; 2.2359x over previous
//
#include <hip/hip_runtime.h>

#define NF    50000
#define PADP  50001
#define KN    9
#define KTOT  2304
#define NCHUNK 782
#define BM2   256
#define NBLK2 196        // 196*256 = 50176 >= 50000; <= 256 CUs -> 1 round
#define NKT   36         // 2304/64 K-tiles
#define BUF   65536      // one dbuf: A 256x128B (32KB) + B 256x128B (32KB)
#define BOFF  32768
#define IDXOFF2 131072   // idx cache: 256*9*4 = 9216 -> LDS total 140288

// ---- ws layout (bytes) ----
#define WT_OFF   0u
#define FLAG_OFF 1179648u
#define CNT_OFF  1179904u
#define PADX_OFF 1183744u

typedef float f32x4 __attribute__((ext_vector_type(4)));
typedef __bf16 bf16x8 __attribute__((ext_vector_type(8)));

typedef const __attribute__((address_space(1))) unsigned int* gas_t;
typedef __attribute__((address_space(3))) unsigned int* las_t;

static __device__ __forceinline__ void gll16(const void* g, void* l) {
  __builtin_amdgcn_global_load_lds((gas_t)g, (las_t)l, 16, 0, 0);
}

static __device__ __forceinline__ unsigned short f2bf(float f) {
  unsigned int u = __builtin_bit_cast(unsigned int, f);
  u = u + 0x7fffu + ((u >> 16) & 1u);      // RNE
  return (unsigned short)(u >> 16);
}

// ---------- preprocessing (unchanged from R6) ----------

__global__ void k_prep(const float* __restrict__ w, unsigned short* __restrict__ wt,
                       const unsigned char* __restrict__ pad, int* __restrict__ cnt,
                       const unsigned int* __restrict__ raw, int* __restrict__ flag) {
  if (blockIdx.x < 256) {
    int o = blockIdx.x;
    int i = threadIdx.x;
    const float* wr = w + (o * 256 + i) * 9;
    float wv[9];
    float s = 0.f;
#pragma unroll
    for (int k = 0; k < 9; ++k) { wv[k] = wr[k]; s += wv[k] * wv[k]; }
#pragma unroll
    for (int d = 32; d >= 1; d >>= 1) s += __shfl_xor(s, d);
    __shared__ float red[4];
    if ((i & 63) == 0) red[i >> 6] = s;
    __syncthreads();
    float dc = rsqrtf(red[0] + red[1] + red[2] + red[3] + 1e-8f);
#pragma unroll
    for (int k = 0; k < 9; ++k)
      wt[o * KTOT + k * 256 + i] = f2bf(wv[k] * dc);
  } else {
    int cb = blockIdx.x - 256;
    int t = cb * 256 + threadIdx.x;
    bool ip = (t < PADP) ? (pad[t] != 0) : true;
    unsigned long long m = __ballot(ip);
    int c = t >> 6;
    if ((threadIdx.x & 63) == 0 && c < NCHUNK) cnt[c] = __popcll(m);
    if (cb == 0 && threadIdx.x < 64) {
      unsigned int v = raw[threadIdx.x * 2 + 1];
      unsigned long long nz = __ballot(v != 0u);
      if (threadIdx.x == 0) flag[0] = (nz == 0ull) ? 1 : 0;
    }
  }
}

__global__ __launch_bounds__(256) void k_rankpadx(
    const float* __restrict__ x, const unsigned char* __restrict__ pad,
    const int* __restrict__ cnt, unsigned short* __restrict__ padx) {
  const int c = blockIdx.x;
  const int tid = threadIdx.x, w = tid >> 6, lane = tid & 63;
  int s = 0;
  for (int i = tid; i < c; i += 256) s += cnt[i];
#pragma unroll
  for (int d = 32; d >= 1; d >>= 1) s += __shfl_xor(s, d);
  __shared__ int red[4];
  __shared__ int rnk[64];
  if (lane == 0) red[w] = s;
  __syncthreads();
  const int S = red[0] + red[1] + red[2] + red[3];
  if (w == 0) {
    int p = c * 64 + lane;
    bool ip = (p < PADP) ? (pad[p] != 0) : true;
    unsigned long long m = __ballot(ip);
    int before = __popcll(m & ((1ull << lane) - 1ull));
    rnk[lane] = ip ? -1 : (p - (S + before));
  }
  __syncthreads();
  const int col = lane * 4;
#pragma unroll
  for (int i = 0; i < 16; ++i) {
    int rl = i * 4 + w;
    int pp = c * 64 + rl;
    if (pp >= PADP) continue;
    int rr = rnk[rl];
    ushort4 ov;
    if (rr < 0) { ov.x = 0; ov.y = 0; ov.z = 0; ov.w = 0; }
    else {
      const float4 v = *(const float4*)(x + rr * 256 + col);
      ov.x = f2bf(v.x); ov.y = f2bf(v.y); ov.z = f2bf(v.z); ov.w = f2bf(v.w);
    }
    *(ushort4*)(padx + pp * 256 + col) = ov;
  }
}

// ---------- main gathered GEMM: m201-style 8-phase port ----------
// BM=256 x BN=256 x BK=64, 512 thr (8 waves 2M x 4N), wave-tile 128x64
// (acc 8x4 f32x4 = 128 VGPR). Grid 196 (1 round over 256 CUs).
// LDS: 2 dbuf x (A 256rows x 128B + B 256cols x 128B) + idx cache = 137KB.
// Rows are 128B = 8 slots of 16B; slot swizzle: LDS slot s of row r holds
// global slot s ^ (r&7) (pre-swizzled gll16 source; reads XOR back -> 2-way max).
// Per K-tile 4 phases: P0 [ds A(q0,kk0)+B(kk0) | stage HA0(kt+1)->other.A]
//                      P1 [ds A(q1,kk0)        | stage HA1(kt+1)->other.A]
//                      P2 [ds A(q0,kk1)+B(kk1) | idx refresh every 4th kt]
//                      P3 [ds A(q1,kk1)        | stage HB0+HB1(kt+2)->cur.B; vmcnt(4)]
// Each phase: stage/reads -> s_barrier -> lgkmcnt(0) -> setprio(1) 16 MFMA.
// Safety: every stage targets a region whose last reader finished >=1 barrier
// earlier (A: other-buf, last read prev kt P3; B: cur-buf, last read P2).
// Residency: vmcnt(4) at P3 leaves only HB(kt+2) in flight.
__global__ __launch_bounds__(512, 2) void k_main(
    const unsigned short* __restrict__ padx,   // [50001][256] bf16
    const unsigned short* __restrict__ wt,     // [256][2304] bf16
    const void* __restrict__ nbr,              // [50000][9] int64 or int32
    const int* __restrict__ flag,
    const float* __restrict__ bias,            // [256]
    float* __restrict__ out) {                 // [50000][256] f32
  __shared__ __align__(16) unsigned char sm[140288];
  const int tid = threadIdx.x;
  const int wv = tid >> 6, lane = tid & 63;
  const int m0 = blockIdx.x * BM2;
  int* idxl = (int*)(sm + IDXOFF2);

  const int q = lane & 15, hi = lane >> 4;
  const int wm = wv >> 2, wn = wv & 3;

  // bias preload (drained by prologue vmcnt(0))
  float bv[4];
#pragma unroll
  for (int ni = 0; ni < 4; ++ni) bv[ni] = bias[wn * 64 + ni * 16 + q];

  // idx cache: 256 rows x 9 neighbors (faces clamped)
  const bool f64 = (flag[0] != 0);
  const long long* n64 = (const long long*)nbr;
  const int* n32 = (const int*)nbr;
  for (int e = tid; e < BM2 * 9; e += 512) {
    int f = m0 + e / 9;
    if (f >= NF) f = NF - 1;
    int k = e - (e / 9) * 9;
    idxl[e] = f64 ? (int)n64[f * KN + k] : n32[f * KN + k];
  }
  __syncthreads();

  // ---- staging geometry ----
  const int swsrc = ((tid & 7) ^ ((tid >> 3) & 7)) * 8;  // pre-swizzled src slot (elems)
  const int fl0 = tid >> 3;                              // staged row/col base 0..63
  const int rb0 = fl0 * 9, rb1 = (fl0 + 64) * 9, rb2 = (fl0 + 128) * 9, rb3 = (fl0 + 192) * 9;
  const unsigned short* wtb00 = wt + (fl0      ) * KTOT + swsrc;
  const unsigned short* wtb01 = wt + (fl0 +  64) * KTOT + swsrc;
  const unsigned short* wtb10 = wt + (fl0 + 128) * KTOT + swsrc;
  const unsigned short* wtb11 = wt + (fl0 + 192) * KTOT + swsrc;

  // ---- fragment read offsets (bytes within a buf) ----
  const int q7 = q & 7;
  const int aof0 = wm * 16384 + q * 128 + ((hi    ) ^ q7) * 16;   // kk=0
  const int aof1 = wm * 16384 + q * 128 + ((4 + hi) ^ q7) * 16;   // kk=1
  const int bof0 = BOFF + (wn * 64 + q) * 128 + ((hi    ) ^ q7) * 16;
  const int bof1 = BOFF + (wn * 64 + q) * 128 + ((4 + hi) ^ q7) * 16;

  f32x4 acc[8][4];
#pragma unroll
  for (int a = 0; a < 8; ++a)
#pragma unroll
    for (int b = 0; b < 4; ++b) {
      acc[a][b][0] = 0.f; acc[a][b][1] = 0.f; acc[a][b][2] = 0.f; acc[a][b][3] = 0.f;
    }

  bf16x8 af[8], bq[4];
  int pA0 = idxl[rb0], pA1 = idxl[rb1], pA2 = idxl[rb2], pA3 = idxl[rb3];  // g=0

  // ---- prologue: stage HB(0), HA(0), HB(1); drain; barrier ----
  gll16(wtb00, sm + BOFF + tid * 16);
  gll16(wtb01, sm + BOFF + 8192 + tid * 16);
  gll16(wtb10, sm + BOFF + 16384 + tid * 16);
  gll16(wtb11, sm + BOFF + 24576 + tid * 16);
  gll16(padx + pA0 * 256 + swsrc, sm + tid * 16);
  gll16(padx + pA1 * 256 + swsrc, sm + 8192 + tid * 16);
  gll16(padx + pA2 * 256 + swsrc, sm + 16384 + tid * 16);
  gll16(padx + pA3 * 256 + swsrc, sm + 24576 + tid * 16);
  gll16(wtb00 + 64, sm + BUF + BOFF + tid * 16);
  gll16(wtb01 + 64, sm + BUF + BOFF + 8192 + tid * 16);
  gll16(wtb10 + 64, sm + BUF + BOFF + 16384 + tid * 16);
  gll16(wtb11 + 64, sm + BUF + BOFF + 24576 + tid * 16);
  asm volatile("s_waitcnt vmcnt(0)" ::: "memory");
  __builtin_amdgcn_s_barrier();

#define LD(p) (*(const bf16x8*)(p))
#define SB __builtin_amdgcn_sched_barrier(0);
#define MF(MI, AFI) \
  acc[MI][0] = __builtin_amdgcn_mfma_f32_16x16x32_bf16(af[AFI], bq[0], acc[MI][0], 0,0,0); \
  acc[MI][1] = __builtin_amdgcn_mfma_f32_16x16x32_bf16(af[AFI], bq[1], acc[MI][1], 0,0,0); \
  acc[MI][2] = __builtin_amdgcn_mfma_f32_16x16x32_bf16(af[AFI], bq[2], acc[MI][2], 0,0,0); \
  acc[MI][3] = __builtin_amdgcn_mfma_f32_16x16x32_bf16(af[AFI], bq[3], acc[MI][3], 0,0,0);
#define TAIL(M0,M1,M2,M3) \
  SB __builtin_amdgcn_s_barrier(); \
  asm volatile("s_waitcnt lgkmcnt(0)" ::: "memory"); SB \
  __builtin_amdgcn_s_setprio(1); \
  MF(M0,M0) MF(M1,M1) MF(M2,M2) MF(M3,M3) \
  __builtin_amdgcn_s_setprio(0); \
  SB __builtin_amdgcn_s_barrier();

#define PH0(CUR,OTH,C0A) { \
  const unsigned char* cb = sm + (CUR)*BUF; \
  af[0]=LD(cb+aof0); af[1]=LD(cb+aof0+2048); af[2]=LD(cb+aof0+4096); af[3]=LD(cb+aof0+6144); \
  bq[0]=LD(cb+bof0); bq[1]=LD(cb+bof0+2048); bq[2]=LD(cb+bof0+4096); bq[3]=LD(cb+bof0+6144); \
  gll16(padx + pA0*256 + (C0A) + swsrc, sm + (OTH)*BUF + tid*16); \
  gll16(padx + pA1*256 + (C0A) + swsrc, sm + (OTH)*BUF + 8192 + tid*16); \
  TAIL(0,1,2,3) }

#define PH1(CUR,OTH,C0A) { \
  const unsigned char* cb = sm + (CUR)*BUF; \
  af[4]=LD(cb+aof0+8192); af[5]=LD(cb+aof0+10240); af[6]=LD(cb+aof0+12288); af[7]=LD(cb+aof0+14336); \
  gll16(padx + pA2*256 + (C0A) + swsrc, sm + (OTH)*BUF + 16384 + tid*16); \
  gll16(padx + pA3*256 + (C0A) + swsrc, sm + (OTH)*BUF + 24576 + tid*16); \
  TAIL(4,5,6,7) }

#define PH2(CUR, DOREF) { \
  const unsigned char* cb = sm + (CUR)*BUF; \
  af[0]=LD(cb+aof1); af[1]=LD(cb+aof1+2048); af[2]=LD(cb+aof1+4096); af[3]=LD(cb+aof1+6144); \
  bq[0]=LD(cb+bof1); bq[1]=LD(cb+bof1+2048); bq[2]=LD(cb+bof1+4096); bq[3]=LD(cb+bof1+6144); \
  if (DOREF) { int gn = g4 + 1; if (gn > 8) gn = 8; \
    pA0 = idxl[rb0+gn]; pA1 = idxl[rb1+gn]; pA2 = idxl[rb2+gn]; pA3 = idxl[rb3+gn]; } \
  TAIL(0,1,2,3) }

#define PH3(CUR, KB) { \
  const unsigned char* cb = sm + (CUR)*BUF; \
  af[4]=LD(cb+aof1+8192); af[5]=LD(cb+aof1+10240); af[6]=LD(cb+aof1+12288); af[7]=LD(cb+aof1+14336); \
  gll16(wtb00 + (KB), sm + (CUR)*BUF + BOFF + tid*16); \
  gll16(wtb01 + (KB), sm + (CUR)*BUF + BOFF + 8192 + tid*16); \
  gll16(wtb10 + (KB), sm + (CUR)*BUF + BOFF + 16384 + tid*16); \
  gll16(wtb11 + (KB), sm + (CUR)*BUF + BOFF + 24576 + tid*16); \
  asm volatile("s_waitcnt vmcnt(4)" ::: "memory"); \
  TAIL(4,5,6,7) }

#pragma unroll 1
  for (int g4 = 0; g4 < 9; ++g4) {
    const int ktb = g4 * 4;
    int u;
    // kt = ktb+0 (buf0), stages HA(kt+1) c0=64, HB(kt+2)
    PH0(0,1,64) PH1(0,1,64) PH2(0,0)
    u = ktb + 2; if (u > 35) u = 35;
    PH3(0, u*64)
    // kt = ktb+1 (buf1), c0=128
    PH0(1,0,128) PH1(1,0,128) PH2(1,0)
    u = ktb + 3; if (u > 35) u = 35;
    PH3(1, u*64)
    // kt = ktb+2 (buf0), c0=192, idx refresh for g4+1
    PH0(0,1,192) PH1(0,1,192) PH2(0,1)
    u = ktb + 4; if (u > 35) u = 35;
    PH3(0, u*64)
    // kt = ktb+3 (buf1), c0=0 (next neighbor's first tile)
    PH0(1,0,0) PH1(1,0,0) PH2(1,0)
    u = ktb + 5; if (u > 35) u = 35;
    PH3(1, u*64)
  }
#undef PH0
#undef PH1
#undef PH2
#undef PH3
#undef TAIL
#undef MF
#undef LD
#undef SB
  asm volatile("s_waitcnt vmcnt(0)" ::: "memory");

  // ---- epilogue: bias + store (D: col = q, row = hi*4 + rr) ----
#pragma unroll
  for (int ni = 0; ni < 4; ++ni) {
    const int col = wn * 64 + ni * 16 + q;
#pragma unroll
    for (int mi = 0; mi < 8; ++mi) {
#pragma unroll
      for (int rr = 0; rr < 4; ++rr) {
        const int row = m0 + wm * 128 + mi * 16 + hi * 4 + rr;
        if (row < NF) out[row * 256 + col] = acc[mi][ni][rr] + bv[ni];
      }
    }
  }
}

extern "C" void kernel_launch(void* const* d_in, const int* in_sizes, int n_in,
                              void* d_out, int out_size, void* d_ws, size_t ws_size,
                              hipStream_t stream) {
  const float* x = (const float*)d_in[0];
  const float* wfull = (const float*)d_in[1];
  const float* bias = (const float*)d_in[2];
  const void* nbr = d_in[3];
  const unsigned char* pad = (const unsigned char*)d_in[4];
  float* out = (float*)d_out;
  char* ws = (char*)d_ws;

  unsigned short* wt   = (unsigned short*)(ws + WT_OFF);
  int* flag            = (int*)(ws + FLAG_OFF);
  int* cnt             = (int*)(ws + CNT_OFF);
  unsigned short* padx = (unsigned short*)(ws + PADX_OFF);

  k_prep<<<452, 256, 0, stream>>>(wfull, wt, pad, cnt, (const unsigned int*)nbr, flag);
  k_rankpadx<<<NCHUNK, 256, 0, stream>>>(x, pad, cnt, padx);
  k_main<<<NBLK2, 512, 0, stream>>>(padx, wt, nbr, flag, bias, out);
}